// Round 4
// baseline (7376.672 us; speedup 1.0000x reference)
//
#include <hip/hip_runtime.h>

#define SEQ   120
#define WARM  96
#define FLEN  24
#define HDIM  256

typedef __attribute__((ext_vector_type(8))) short bf16x8;
typedef __attribute__((ext_vector_type(4))) float floatx4;
typedef unsigned int uint;

// ws layout (bytes):
//   WHI  [0, 512K)        bf16 frag-linear: unit = (((s*2+uc)*4+g)*8+kt)*64 + kq*16 + n, short = unit*8+j
//   WLO  [512K, 1M)       same layout
//   BB   [1M, +4K)        f32 b_ih+b_hh
//   WI   [1M+4K, +4K)     f32 W_ih col
//   BAR  [1M+8K, +128)    uint bar[32]
//   HG   [1M+16K, +4M)    uint h packed (hi<<16|lo), 2 parities x 32 rg x 16384
#define WHI_OFF 0
#define WLO_OFF (512 * 1024)
#define BB_OFF  (1024 * 1024)
#define WI_OFF  (1024 * 1024 + 4096)
#define BAR_OFF (1024 * 1024 + 8192)
#define HG_OFF  (1024 * 1024 + 16384)
#define HG_PAR  524288              // uints per parity

#define LDS_BYTES 131328            // wlo 64K | hhi 32K | hlo 32K | y 256B

__device__ __forceinline__ short f2bf(float v) {
    unsigned u = __float_as_uint(v);
    u += 0x7FFF + ((u >> 16) & 1);              // RNE
    return (short)(u >> 16);
}
__device__ __forceinline__ float bf2f(short s) {
    return __uint_as_float(((unsigned)(unsigned short)s) << 16);
}
__device__ __forceinline__ float fast_sig(float x) {
    return 1.0f / (1.0f + __expf(-x));
}
__device__ __forceinline__ float fast_tanh(float x) {
    return 1.0f - 2.0f / (__expf(2.0f * x) + 1.0f);
}

__global__ __launch_bounds__(256) void lstm_prep(
    const float* __restrict__ W_ih, const float* __restrict__ W_hh,
    const float* __restrict__ b_ih, const float* __restrict__ b_hh,
    const float* __restrict__ h0, unsigned char* __restrict__ ws)
{
    int tid = blockIdx.x * 256 + threadIdx.x;       // grid 2048*256 = 524288
    if (tid < 262144) {
        int col = tid >> 8, k = tid & 255;          // col = gate*256+unit
        float v  = W_hh[tid];
        short hi = f2bf(v);
        short lo = f2bf(v - bf2f(hi));
        int g = col >> 8, rem = col & 255;
        int s = rem >> 5, uo = rem & 31, uc = uo >> 4, n = uo & 15;
        int kt = k >> 5, kq = (k >> 3) & 3, j = k & 7;
        size_t unit = ((((size_t)(s * 2 + uc) * 4 + g) * 8 + kt) * 64 + kq * 16 + n);
        ((short*)(ws + WHI_OFF))[unit * 8 + j] = hi;
        ((short*)(ws + WLO_OFF))[unit * 8 + j] = lo;
    }
    if (tid < 524288) {                              // pack h0 -> parity 0
        int row = tid >> 8, k = tid & 255;
        float v  = h0[tid];
        short hi = f2bf(v);
        short lo = f2bf(v - bf2f(hi));
        int rg = row >> 6, rt = (row >> 4) & 3, rlow = row & 15;
        int kt = k >> 5, kq = (k >> 3) & 3, kk = k & 7;
        size_t idx = (size_t)rg * 16384 + (size_t)((((rt * 8 + kt) * 4 + kq) * 16 + rlow) * 8 + kk);
        ((uint*)(ws + HG_OFF))[idx] =
            ((uint)(unsigned short)hi << 16) | (uint)(unsigned short)lo;
    }
    if (tid < 1024) {
        ((float*)(ws + BB_OFF))[tid] = b_ih[tid] + b_hh[tid];
        ((float*)(ws + WI_OFF))[tid] = W_ih[tid];
    }
    if (tid < 32) ((uint*)(ws + BAR_OFF))[tid] = 0;
}

__global__ void __launch_bounds__(512, 2) lstm_main(
    const float* __restrict__ x, const float* __restrict__ c0,
    unsigned char* __restrict__ ws, const float* __restrict__ fcw,
    const float* __restrict__ fcb, float* __restrict__ out)
{
    extern __shared__ char smem[];
    short* wlo_s = (short*)smem;                  // 32768 shorts (64 KB)
    short* hhi_s = (short*)(smem + 65536);        // 16384 shorts
    short* hlo_s = (short*)(smem + 98304);        // 16384 shorts
    float* y_s   = (float*)(smem + 131072);       // 64 floats

    const int tid  = threadIdx.x;
    const int blk  = blockIdx.x;
    const int rg   = blk & 31;                    // row-group: 64 rows
    const int s    = blk >> 5;                    // unit-slice: 32 units
    const int wv   = tid >> 6, lane = tid & 63;
    const int quad = lane >> 4, nof = lane & 15;
    const int uc   = wv & 1, rt = wv >> 1;        // wave = (row-tile rt, unit-chunk uc)

    const short* whi_g = (const short*)(ws + WHI_OFF);
    const float* bb    = (const float*)(ws + BB_OFF);
    const float* wi    = (const float*)(ws + WI_OFF);
    uint* bar          = (uint*)(ws + BAR_OFF);
    uint* hg           = (uint*)(ws + HG_OFF);

    // ---- stage W-lo slice -> LDS (64 KB contiguous) ----
    {
        const uint4* src = (const uint4*)(ws + WLO_OFF) + (size_t)s * 4096;
        uint4* dst = (uint4*)wlo_s;
        for (int i = tid; i < 4096; i += 512) dst[i] = src[i];
    }
    // ---- W-hi fragments -> registers (32 x 16B per lane) ----
    bf16x8 bhi[4][8];
    {
        const bf16x8* src = (const bf16x8*)whi_g;
        #pragma unroll
        for (int g = 0; g < 4; ++g)
            #pragma unroll
            for (int kt = 0; kt < 8; ++kt)
                bhi[g][kt] = src[(size_t)(((s * 2 + uc) * 4 + g) * 8 + kt) * 64 + lane];
    }

    // ---- per-thread constants ----
    const int u = s * 32 + uc * 16 + nof;         // owned hidden unit (elementwise)
    float bbg[4], wig[4];
    #pragma unroll
    for (int g = 0; g < 4; ++g) { bbg[g] = bb[g * 256 + u]; wig[g] = wi[g * 256 + u]; }
    const int kbase = (tid >> 6) * 32 + ((tid >> 4) & 3) * 8;  // staging k-chunk
    float fcw8[8];
    #pragma unroll
    for (int j = 0; j < 8; ++j) fcw8[j] = fcw[kbase + j];
    const float fcb0 = fcb[0];
    float c[4];
    #pragma unroll
    for (int i = 0; i < 4; ++i)
        c[i] = c0[(rg * 64 + rt * 16 + quad * 4 + i) * HDIM + u];
    const int kt_u = u >> 5, kq_u = (u >> 3) & 3, kk_u = u & 7;
    const int rlow_t = tid & 15;
    if (tid < 64) y_s[tid] = 0.f;
    __syncthreads();

    for (int t = 0; t <= SEQ; ++t) {
        const uint par = (uint)t & 1u;
        const uint* __restrict__ hsrc = hg + (size_t)par * HG_PAR + (size_t)rg * 16384;

        float xin[4];
        if (t < WARM) {
            #pragma unroll
            for (int i = 0; i < 4; ++i)
                xin[i] = x[(rg * 64 + rt * 16 + quad * 4 + i) * SEQ + t];
        }

        // ---- staging: h(t-1) global -> LDS frags (+ y accumulation) ----
        #pragma unroll
        for (int jj = 0; jj < 4; ++jj) {
            const int w = tid + 512 * jj;
            uint4 a = *(const uint4*)(hsrc + (size_t)w * 8);
            uint4 b = *(const uint4*)(hsrc + (size_t)w * 8 + 4);
            uint4 hi4, lo4;
            hi4.x = (a.x >> 16) | (a.y & 0xFFFF0000u);
            lo4.x = (a.x & 0xFFFFu) | (a.y << 16);
            hi4.y = (a.z >> 16) | (a.w & 0xFFFF0000u);
            lo4.y = (a.z & 0xFFFFu) | (a.w << 16);
            hi4.z = (b.x >> 16) | (b.y & 0xFFFF0000u);
            lo4.z = (b.x & 0xFFFFu) | (b.y << 16);
            hi4.w = (b.z >> 16) | (b.w & 0xFFFF0000u);
            lo4.w = (b.z & 0xFFFFu) | (b.w << 16);
            *(uint4*)(hhi_s + (size_t)w * 8) = hi4;
            *(uint4*)(hlo_s + (size_t)w * 8) = lo4;
            if (t >= WARM) {
                uint q[8] = {a.x, a.y, a.z, a.w, b.x, b.y, b.z, b.w};
                float p = 0.f;
                #pragma unroll
                for (int j = 0; j < 8; ++j) {
                    float hv = __uint_as_float(q[j] & 0xFFFF0000u) +
                               __uint_as_float(q[j] << 16);
                    p = fmaf(fcw8[j], hv, p);
                }
                atomicAdd(&y_s[jj * 16 + rlow_t], p);
            }
        }
        __syncthreads();

        // ---- write out y(t-1) for forecast steps ----
        if (t >= WARM + 1 && s == 0 && tid < 64)
            out[(rg * 64 + tid) * FLEN + (t - (WARM + 1))] = y_s[tid] + fcb0;
        if (t == SEQ) break;

        // ---- MFMA: gates = h @ W^T (3-pass hi/lo), W-hi from regs, W-lo LDS ----
        floatx4 acc[4];
        #pragma unroll
        for (int g = 0; g < 4; ++g) acc[g] = (floatx4){0.f, 0.f, 0.f, 0.f};
        #pragma unroll
        for (int kt = 0; kt < 8; ++kt) {
            bf16x8 ah = *(const bf16x8*)(hhi_s + (rt * 8 + kt) * 512 + lane * 8);
            bf16x8 al = *(const bf16x8*)(hlo_s + (rt * 8 + kt) * 512 + lane * 8);
            #pragma unroll
            for (int g = 0; g < 4; ++g) {
                bf16x8 bl = *(const bf16x8*)(wlo_s + ((uc * 4 + g) * 8 + kt) * 512 + lane * 8);
                acc[g] = __builtin_amdgcn_mfma_f32_16x16x32_bf16(ah, bhi[g][kt], acc[g], 0, 0, 0);
                acc[g] = __builtin_amdgcn_mfma_f32_16x16x32_bf16(al, bhi[g][kt], acc[g], 0, 0, 0);
                acc[g] = __builtin_amdgcn_mfma_f32_16x16x32_bf16(ah, bl,         acc[g], 0, 0, 0);
            }
        }

        // ---- elementwise LSTM (thread-local on C-fragments) ----
        uint* __restrict__ hdst = hg + (size_t)(1u - par) * HG_PAR + (size_t)rg * 16384;
        #pragma unroll
        for (int i = 0; i < 4; ++i) {
            float inr = (t < WARM) ? xin[i] : (y_s[rt * 16 + quad * 4 + i] + fcb0);
            float gi = acc[0][i] + bbg[0] + inr * wig[0];
            float gf = acc[1][i] + bbg[1] + inr * wig[1];
            float gg = acc[2][i] + bbg[2] + inr * wig[2];
            float go = acc[3][i] + bbg[3] + inr * wig[3];
            float cn = fast_sig(gf) * c[i] + fast_sig(gi) * fast_tanh(gg);
            c[i] = cn;
            float h = fast_sig(go) * fast_tanh(cn);
            short hi = f2bf(h);
            short lo = f2bf(h - bf2f(hi));
            int rlow = quad * 4 + i;
            hdst[(size_t)((((rt * 8 + kt_u) * 4 + kq_u) * 16 + rlow) * 8 + kk_u)] =
                ((uint)(unsigned short)hi << 16) | (uint)(unsigned short)lo;
        }

        __threadfence();           // h(t) device-visible (L2 writeback)
        __syncthreads();
        if (tid < 64) y_s[tid] = 0.f;
        if (tid == 0) {
            __hip_atomic_fetch_add(&bar[rg], 1u, __ATOMIC_RELEASE, __HIP_MEMORY_SCOPE_AGENT);
            const uint target = 8u * (uint)(t + 1);
            while (__hip_atomic_load(&bar[rg], __ATOMIC_ACQUIRE, __HIP_MEMORY_SCOPE_AGENT) < target)
                __builtin_amdgcn_s_sleep(2);
        }
        __syncthreads();
    }
}

extern "C" void kernel_launch(void* const* d_in, const int* in_sizes, int n_in,
                              void* d_out, int out_size, void* d_ws, size_t ws_size,
                              hipStream_t stream) {
    const float* x    = (const float*)d_in[0];
    const float* h0   = (const float*)d_in[1];
    const float* c0   = (const float*)d_in[2];
    const float* W_ih = (const float*)d_in[3];
    const float* W_hh = (const float*)d_in[4];
    const float* b_ih = (const float*)d_in[5];
    const float* b_hh = (const float*)d_in[6];
    const float* fc_w = (const float*)d_in[7];
    const float* fc_b = (const float*)d_in[8];
    float* out = (float*)d_out;
    unsigned char* ws = (unsigned char*)d_ws;

    lstm_prep<<<2048, 256, 0, stream>>>(W_ih, W_hh, b_ih, b_hh, h0, ws);

    static int attr_set = 0;
    if (!attr_set) {
        hipFuncSetAttribute((const void*)lstm_main,
                            hipFuncAttributeMaxDynamicSharedMemorySize, LDS_BYTES);
        attr_set = 1;
    }
    void* args[] = {(void*)&x, (void*)&c0, (void*)&ws, (void*)&fc_w, (void*)&fc_b, (void*)&out};
    hipLaunchCooperativeKernel((const void*)lstm_main, dim3(256), dim3(512),
                               args, LDS_BYTES, stream);
}

// Round 6
// 872.882 us; speedup vs baseline: 8.4509x; 8.4509x over previous
//
#include <hip/hip_runtime.h>

#define SEQ   120
#define WARM  96
#define FLEN  24
#define HDIM  256

typedef __attribute__((ext_vector_type(8))) short bf16x8;
typedef __attribute__((ext_vector_type(4))) float floatx4;
typedef unsigned int uint;
typedef unsigned long long ull;

// ws layout (bytes):
//   WHI  [0, 512K)        bf16 frag-linear W-hi
//   WLO  [512K, 1M)       bf16 frag-linear W-lo
//   BB   [1M, +4K)        f32 b_ih+b_hh
//   WI   [1M+4K, +4K)     f32 W_ih col
//   BAR  [1M+8K, +8K)     uint bar[32], stride 64 uints (256 B)
//   HG   [1M+16K, +4M)    uint h packed (hi<<16|lo), 2 parities x 32 rg x 16384
//   XT   [5M+16K, +960K)  f32 x transposed [t][row]
#define WHI_OFF 0
#define WLO_OFF (512 * 1024)
#define BB_OFF  (1024 * 1024)
#define WI_OFF  (1024 * 1024 + 4096)
#define BAR_OFF (1024 * 1024 + 8192)
#define HG_OFF  (1024 * 1024 + 16384)
#define HG_PAR  524288              // uints per parity
#define XT_OFF  (HG_OFF + 4 * 1024 * 1024)

#define LDS_BYTES 131328            // wlo 64K | hhi 32K | hlo 32K | y 256B

__device__ __forceinline__ short f2bf(float v) {
    unsigned u = __float_as_uint(v);
    u += 0x7FFF + ((u >> 16) & 1);              // RNE
    return (short)(u >> 16);
}
__device__ __forceinline__ float bf2f(short s) {
    return __uint_as_float(((unsigned)(unsigned short)s) << 16);
}
__device__ __forceinline__ float fast_sig(float x) {
    return 1.0f / (1.0f + __expf(-x));
}
__device__ __forceinline__ float fast_tanh(float x) {
    return 1.0f - 2.0f / (__expf(2.0f * x) + 1.0f);
}

// LLC-coherent (cross-XCD) accesses: relaxed agent-scope atomics lower to
// global_load/store with device-scope SC bits (L2 bypass, serialize at LLC),
// no buffer_wbl2 / buffer_inv, and the compiler tracks deps (auto waitcnt).
__device__ __forceinline__ ull load_llc64(const ull* p) {
    return __hip_atomic_load(p, __ATOMIC_RELAXED, __HIP_MEMORY_SCOPE_AGENT);
}
__device__ __forceinline__ void store_llc32(uint* p, uint v) {
    __hip_atomic_store(p, v, __ATOMIC_RELAXED, __HIP_MEMORY_SCOPE_AGENT);
}

__global__ __launch_bounds__(256) void lstm_prep(
    const float* __restrict__ W_ih, const float* __restrict__ W_hh,
    const float* __restrict__ b_ih, const float* __restrict__ b_hh,
    const float* __restrict__ h0, const float* __restrict__ x,
    unsigned char* __restrict__ ws)
{
    int tid = blockIdx.x * 256 + threadIdx.x;       // grid 2048*256 = 524288
    if (tid < 262144) {
        int col = tid >> 8, k = tid & 255;          // col = gate*256+unit
        float v  = W_hh[tid];
        short hi = f2bf(v);
        short lo = f2bf(v - bf2f(hi));
        int g = col >> 8, rem = col & 255;
        int s = rem >> 5, uo = rem & 31, uc = uo >> 4, n = uo & 15;
        int kt = k >> 5, kq = (k >> 3) & 3, j = k & 7;
        size_t unit = ((((size_t)(s * 2 + uc) * 4 + g) * 8 + kt) * 64 + kq * 16 + n);
        ((short*)(ws + WHI_OFF))[unit * 8 + j] = hi;
        ((short*)(ws + WLO_OFF))[unit * 8 + j] = lo;
    }
    if (tid < 524288) {                              // pack h0 -> parity 0
        int row = tid >> 8, k = tid & 255;
        float v  = h0[tid];
        short hi = f2bf(v);
        short lo = f2bf(v - bf2f(hi));
        int rg = row >> 6, rt = (row >> 4) & 3, rlow = row & 15;
        int kt = k >> 5, kq = (k >> 3) & 3, kk = k & 7;
        size_t idx = (size_t)rg * 16384 + (size_t)((((rt * 8 + kt) * 4 + kq) * 16 + rlow) * 8 + kk);
        ((uint*)(ws + HG_OFF))[idx] =
            ((uint)(unsigned short)hi << 16) | (uint)(unsigned short)lo;
    }
    if (tid < 2048 * SEQ) {                          // x transpose -> [t][row]
        int row = tid / SEQ, tt = tid % SEQ;
        ((float*)(ws + XT_OFF))[tt * 2048 + row] = x[tid];
    }
    if (tid < 1024) {
        ((float*)(ws + BB_OFF))[tid] = b_ih[tid] + b_hh[tid];
        ((float*)(ws + WI_OFF))[tid] = W_ih[tid];
    }
    if (tid < 32) ((uint*)(ws + BAR_OFF))[tid * 64] = 0;
}

__global__ void __launch_bounds__(512, 2) lstm_main(
    const float* __restrict__ c0, unsigned char* __restrict__ ws,
    const float* __restrict__ fcw, const float* __restrict__ fcb,
    float* __restrict__ out)
{
    extern __shared__ char smem[];
    short* wlo_s = (short*)smem;                  // 32768 shorts (64 KB)
    short* hhi_s = (short*)(smem + 65536);        // 16384 shorts
    short* hlo_s = (short*)(smem + 98304);        // 16384 shorts
    float* y_s   = (float*)(smem + 131072);       // 64 floats

    const int tid  = threadIdx.x;
    const int blk  = blockIdx.x;
    const int rg   = blk & 31;                    // row-group: 64 rows
    const int s    = blk >> 5;                    // unit-slice: 32 units
    const int wv   = tid >> 6, lane = tid & 63;
    const int quad = lane >> 4, nof = lane & 15;
    const int uc   = wv & 1, rt = wv >> 1;        // wave = (row-tile rt, unit-chunk uc)

    const short* whi_g = (const short*)(ws + WHI_OFF);
    const float* bb    = (const float*)(ws + BB_OFF);
    const float* wi    = (const float*)(ws + WI_OFF);
    const float* xT    = (const float*)(ws + XT_OFF);
    uint* bar          = (uint*)(ws + BAR_OFF);
    uint* hg           = (uint*)(ws + HG_OFF);

    // ---- stage W-lo slice -> LDS (64 KB contiguous) ----
    {
        const uint4* src = (const uint4*)(ws + WLO_OFF) + (size_t)s * 4096;
        uint4* dst = (uint4*)wlo_s;
        for (int i = tid; i < 4096; i += 512) dst[i] = src[i];
    }
    // ---- W-hi fragments -> registers/AGPRs (32 x 16B per lane) ----
    bf16x8 bhi[4][8];
    {
        const bf16x8* src = (const bf16x8*)whi_g;
        #pragma unroll
        for (int g = 0; g < 4; ++g)
            #pragma unroll
            for (int kt = 0; kt < 8; ++kt)
                bhi[g][kt] = src[(size_t)(((s * 2 + uc) * 4 + g) * 8 + kt) * 64 + lane];
    }

    // ---- per-thread constants ----
    const int u = s * 32 + uc * 16 + nof;         // owned hidden unit (elementwise)
    float bbg[4], wig[4];
    #pragma unroll
    for (int g = 0; g < 4; ++g) { bbg[g] = bb[g * 256 + u]; wig[g] = wi[g * 256 + u]; }
    float fcw8[8];
    #pragma unroll
    for (int mm = 0; mm < 2; ++mm)
        #pragma unroll
        for (int cc = 0; cc < 4; ++cc)
            fcw8[mm * 4 + cc] =
                fcw[((((tid >> 7) + 4 * mm) & 7) << 5) + (((tid >> 5) & 3) << 3) +
                    ((tid & 1) << 2) + cc];
    const float fcb0 = fcb[0];
    float c[4];
    #pragma unroll
    for (int i = 0; i < 4; ++i)
        c[i] = c0[(rg * 64 + rt * 16 + quad * 4 + i) * HDIM + u];
    const int kq_u = uc * 2 + (nof >> 3);
    const int kk_u = nof & 7;
    if (tid < 64) y_s[tid] = 0.f;
    __syncthreads();

    for (int t = 0; t <= SEQ; ++t) {
        const uint par = (uint)t & 1u;
        const uint* __restrict__ hsrc = hg + (size_t)par * HG_PAR + (size_t)rg * 16384;

        float4 xv;
        if (t < WARM)
            xv = *(const float4*)(xT + t * 2048 + rg * 64 + rt * 16 + quad * 4);

        // ---- staging: h(t-1) LLC -> LDS frags (+ y partials) ----
        const ull* hsp64 = (const ull*)hsrc + 2 * tid;
        ull e[16];
        #pragma unroll
        for (int m = 0; m < 8; ++m) {
            e[2 * m]     = load_llc64(hsp64 + 1024 * m);
            e[2 * m + 1] = load_llc64(hsp64 + 1024 * m + 1);
        }
        #pragma unroll
        for (int m = 0; m < 8; ++m) {
            uint4 a;
            a.x = (uint)e[2 * m];
            a.y = (uint)(e[2 * m] >> 32);
            a.z = (uint)e[2 * m + 1];
            a.w = (uint)(e[2 * m + 1] >> 32);
            const int base = 4 * tid + 2048 * m;    // short index
            uint2 hi2, lo2;
            hi2.x = (a.x >> 16) | (a.y & 0xFFFF0000u);
            lo2.x = (a.x & 0xFFFFu) | (a.y << 16);
            hi2.y = (a.z >> 16) | (a.w & 0xFFFF0000u);
            lo2.y = (a.z & 0xFFFFu) | (a.w << 16);
            *(uint2*)(hhi_s + base) = hi2;
            *(uint2*)(hlo_s + base) = lo2;
            if (t >= WARM) {
                const int w9 = tid + 512 * m;
                const int row = ((w9 >> 10) << 4) | ((w9 >> 1) & 15);
                const float* f4 = &fcw8[(m & 1) * 4];
                float p;
                p  = f4[0] * (__uint_as_float(a.x & 0xFFFF0000u) + __uint_as_float(a.x << 16));
                p += f4[1] * (__uint_as_float(a.y & 0xFFFF0000u) + __uint_as_float(a.y << 16));
                p += f4[2] * (__uint_as_float(a.z & 0xFFFF0000u) + __uint_as_float(a.z << 16));
                p += f4[3] * (__uint_as_float(a.w & 0xFFFF0000u) + __uint_as_float(a.w << 16));
                atomicAdd(&y_s[row], p);
            }
        }
        __syncthreads();      // h frags + y_s complete

        if (t >= WARM + 1 && s == 0 && tid < 64)
            out[(rg * 64 + tid) * FLEN + (t - (WARM + 1))] = y_s[tid] + fcb0;
        if (t == SEQ) break;

        // ---- MFMA: gates = h @ W^T (3-pass hi/lo), W-hi regs, W-lo LDS ----
        floatx4 acc[4];
        #pragma unroll
        for (int g = 0; g < 4; ++g) acc[g] = (floatx4){0.f, 0.f, 0.f, 0.f};
        #pragma unroll
        for (int kt = 0; kt < 8; ++kt) {
            bf16x8 ah = *(const bf16x8*)(hhi_s + (rt * 8 + kt) * 512 + lane * 8);
            bf16x8 al = *(const bf16x8*)(hlo_s + (rt * 8 + kt) * 512 + lane * 8);
            #pragma unroll
            for (int g = 0; g < 4; ++g) {
                bf16x8 bl = *(const bf16x8*)(wlo_s + ((uc * 4 + g) * 8 + kt) * 512 + lane * 8);
                acc[g] = __builtin_amdgcn_mfma_f32_16x16x32_bf16(ah, bhi[g][kt], acc[g], 0, 0, 0);
                acc[g] = __builtin_amdgcn_mfma_f32_16x16x32_bf16(al, bhi[g][kt], acc[g], 0, 0, 0);
                acc[g] = __builtin_amdgcn_mfma_f32_16x16x32_bf16(ah, bl,         acc[g], 0, 0, 0);
            }
        }

        // ---- elementwise LSTM (thread-local on C-fragments) + LLC h store ----
        uint* __restrict__ hdst = hg + (size_t)(1u - par) * HG_PAR + (size_t)rg * 16384;
        const float xin[4] = {xv.x, xv.y, xv.z, xv.w};
        #pragma unroll
        for (int i = 0; i < 4; ++i) {
            const int rlow = quad * 4 + i;
            float inr = (t < WARM) ? xin[i] : (y_s[rt * 16 + rlow] + fcb0);
            float gi = acc[0][i] + bbg[0] + inr * wig[0];
            float gf = acc[1][i] + bbg[1] + inr * wig[1];
            float gg = acc[2][i] + bbg[2] + inr * wig[2];
            float go = acc[3][i] + bbg[3] + inr * wig[3];
            float cn = fast_sig(gf) * c[i] + fast_sig(gi) * fast_tanh(gg);
            c[i] = cn;
            float h = fast_sig(go) * fast_tanh(cn);
            short hi = f2bf(h);
            short lo = f2bf(h - bf2f(hi));
            store_llc32(hdst + ((((rt * 8 + s) * 4 + kq_u) * 16 + rlow) * 8 + kk_u),
                        ((uint)(unsigned short)hi << 16) | (uint)(unsigned short)lo);
        }
        asm volatile("s_waitcnt vmcnt(0)" ::: "memory");   // h stores at LLC
        __syncthreads();                                    // whole block done

        if (tid < 64) y_s[tid] = 0.f;
        if (tid == 0) {
            __hip_atomic_fetch_add(&bar[rg * 64], 1u, __ATOMIC_RELAXED,
                                   __HIP_MEMORY_SCOPE_AGENT);
            const uint target = 8u * (uint)(t + 1);
            while (__hip_atomic_load(&bar[rg * 64], __ATOMIC_RELAXED,
                                     __HIP_MEMORY_SCOPE_AGENT) < target)
                __builtin_amdgcn_s_sleep(1);
        }
        __syncthreads();
    }
}

extern "C" void kernel_launch(void* const* d_in, const int* in_sizes, int n_in,
                              void* d_out, int out_size, void* d_ws, size_t ws_size,
                              hipStream_t stream) {
    const float* x    = (const float*)d_in[0];
    const float* h0   = (const float*)d_in[1];
    const float* c0   = (const float*)d_in[2];
    const float* W_ih = (const float*)d_in[3];
    const float* W_hh = (const float*)d_in[4];
    const float* b_ih = (const float*)d_in[5];
    const float* b_hh = (const float*)d_in[6];
    const float* fc_w = (const float*)d_in[7];
    const float* fc_b = (const float*)d_in[8];
    float* out = (float*)d_out;
    unsigned char* ws = (unsigned char*)d_ws;

    lstm_prep<<<2048, 256, 0, stream>>>(W_ih, W_hh, b_ih, b_hh, h0, x, ws);

    static int attr_set = 0;
    if (!attr_set) {
        (void)hipFuncSetAttribute((const void*)lstm_main,
                                  hipFuncAttributeMaxDynamicSharedMemorySize, LDS_BYTES);
        attr_set = 1;
    }
    void* args[] = {(void*)&c0, (void*)&ws, (void*)&fc_w, (void*)&fc_b, (void*)&out};
    (void)hipLaunchCooperativeKernel((const void*)lstm_main, dim3(256), dim3(512),
                                     args, LDS_BYTES, stream);
}